// Round 3
// baseline (294.492 us; speedup 1.0000x reference)
//
#include <hip/hip_runtime.h>

#define N_NODES 100000
#define N_EDGES 600000
#define D 128
#define D4 32

#define SCAN_BLK 1024
#define NB ((N_NODES + SCAN_BLK - 1) / SCAN_BLK)  // 98

// ---------------------------------------------------------------------------
// CSR build: counts -> scan -> fill. Int atomics only.
// ---------------------------------------------------------------------------
__global__ __launch_bounds__(256) void hist_kernel(
    const int* __restrict__ dst, int* __restrict__ counts) {
    int i = blockIdx.x * blockDim.x + threadIdx.x;
    if (i < N_EDGES / 4) {
        int4 d = reinterpret_cast<const int4*>(dst)[i];
        atomicAdd(&counts[d.x], 1);
        atomicAdd(&counts[d.y], 1);
        atomicAdd(&counts[d.z], 1);
        atomicAdd(&counts[d.w], 1);
    }
}

// Per-block reduction of counts -> bsum[block]
__global__ __launch_bounds__(SCAN_BLK) void scanA_kernel(
    const int* __restrict__ counts, int* __restrict__ bsum) {
    __shared__ int sm[SCAN_BLK];
    int t = threadIdx.x;
    int i = blockIdx.x * SCAN_BLK + t;
    sm[t] = (i < N_NODES) ? counts[i] : 0;
    __syncthreads();
    for (int off = SCAN_BLK / 2; off > 0; off >>= 1) {
        if (t < off) sm[t] += sm[t + off];
        __syncthreads();
    }
    if (t == 0) bsum[blockIdx.x] = sm[0];
}

// Per-block exclusive scan; block prefix computed in-kernel from bsum
// (parallel 128-wide reduce — replaces the old serial scanB kernel).
__global__ __launch_bounds__(SCAN_BLK) void scanC_kernel(
    const int* __restrict__ counts, const int* __restrict__ bsum,
    int* __restrict__ offsets) {
    __shared__ int sm[SCAN_BLK];
    __shared__ int pre[128];
    int t = threadIdx.x;
    int i = blockIdx.x * SCAN_BLK + t;
    int c = (i < N_NODES) ? counts[i] : 0;
    sm[t] = c;
    if (t < 128) pre[t] = (t < blockIdx.x && t < NB) ? bsum[t] : 0;
    __syncthreads();
    for (int off = 64; off > 0; off >>= 1) {
        if (t < off) pre[t] += pre[t + off];
        __syncthreads();
    }
    for (int off = 1; off < SCAN_BLK; off <<= 1) {
        int v = (t >= off) ? sm[t - off] : 0;
        __syncthreads();
        sm[t] += v;
        __syncthreads();
    }
    if (i < N_NODES) offsets[i] = pre[0] + sm[t] - c;  // exclusive
}

__global__ __launch_bounds__(256) void fill_kernel(
    const int* __restrict__ src, const int* __restrict__ dst,
    const int* __restrict__ offsets, int* __restrict__ cursor,
    int* __restrict__ csr) {
    int i = blockIdx.x * blockDim.x + threadIdx.x;
    if (i < N_EDGES / 4) {
        int4 s = reinterpret_cast<const int4*>(src)[i];
        int4 d = reinterpret_cast<const int4*>(dst)[i];
        int p;
        p = atomicAdd(&cursor[d.x], 1); csr[offsets[d.x] + p] = s.x;
        p = atomicAdd(&cursor[d.y], 1); csr[offsets[d.y] + p] = s.y;
        p = atomicAdd(&cursor[d.z], 1); csr[offsets[d.z] + p] = s.z;
        p = atomicAdd(&cursor[d.w], 1); csr[offsets[d.w] + p] = s.w;
    }
}

// ---------------------------------------------------------------------------
// Fused gather + residual + degree-norm + GEMM.
// Phase 1: 16 groups of 16 lanes; group g owns node n0+g; lane q owns float4
//   slices q and q+16 -> 8 outstanding value loads per 4-edge iteration.
//   Clamp+mask unrolling removes the serial remainder tail.
// Phase 2: thread (j = tid&127, half = tid>>7) computes 8 node outputs from
//   LDS broadcasts; W row streamed from L1/L2.
// ---------------------------------------------------------------------------
#define TN 16

__global__ __launch_bounds__(256, 2) void fused_kernel(
    const float* __restrict__ feat,
    const int* __restrict__ csr,
    const int* __restrict__ offsets,
    const int* __restrict__ counts,
    const float* __restrict__ W,
    const float* __restrict__ b,
    float* __restrict__ out) {
    __shared__ float4 hs[TN][D4];
    const float4* F4 = reinterpret_cast<const float4*>(feat);

    const int n0 = blockIdx.x * TN;

    // ---- Phase 1: gather ----
    {
        const int g = threadIdx.x >> 4;   // group = node 0..15
        const int q = threadIdx.x & 15;   // slice pair q, q+16
        const int n = n0 + g;
        const int row = offsets[n];
        const int degn = counts[n];

        float4 acc0 = F4[(size_t)n * D4 + q];        // residual
        float4 acc1 = F4[(size_t)n * D4 + q + 16];

        const int nit = (degn + 3) >> 2;
        const int dm1 = degn - 1;
        for (int it = 0; it < nit; ++it) {
            const int base = it * 4;
            const int s0 = csr[row + min(base + 0, dm1)];
            const int s1 = csr[row + min(base + 1, dm1)];
            const int s2 = csr[row + min(base + 2, dm1)];
            const int s3 = csr[row + min(base + 3, dm1)];
            // 8 independent value loads in flight
            const float4 a0 = F4[(size_t)s0 * D4 + q];
            const float4 a1 = F4[(size_t)s1 * D4 + q];
            const float4 a2 = F4[(size_t)s2 * D4 + q];
            const float4 a3 = F4[(size_t)s3 * D4 + q];
            const float4 c0 = F4[(size_t)s0 * D4 + q + 16];
            const float4 c1 = F4[(size_t)s1 * D4 + q + 16];
            const float4 c2 = F4[(size_t)s2 * D4 + q + 16];
            const float4 c3 = F4[(size_t)s3 * D4 + q + 16];
            const float m1 = (base + 1 < degn) ? 1.0f : 0.0f;
            const float m2 = (base + 2 < degn) ? 1.0f : 0.0f;
            const float m3 = (base + 3 < degn) ? 1.0f : 0.0f;

            acc0.x += a0.x; acc0.y += a0.y; acc0.z += a0.z; acc0.w += a0.w;
            acc1.x += c0.x; acc1.y += c0.y; acc1.z += c0.z; acc1.w += c0.w;
            acc0.x = fmaf(a1.x, m1, acc0.x); acc0.y = fmaf(a1.y, m1, acc0.y);
            acc0.z = fmaf(a1.z, m1, acc0.z); acc0.w = fmaf(a1.w, m1, acc0.w);
            acc1.x = fmaf(c1.x, m1, acc1.x); acc1.y = fmaf(c1.y, m1, acc1.y);
            acc1.z = fmaf(c1.z, m1, acc1.z); acc1.w = fmaf(c1.w, m1, acc1.w);
            acc0.x = fmaf(a2.x, m2, acc0.x); acc0.y = fmaf(a2.y, m2, acc0.y);
            acc0.z = fmaf(a2.z, m2, acc0.z); acc0.w = fmaf(a2.w, m2, acc0.w);
            acc1.x = fmaf(c2.x, m2, acc1.x); acc1.y = fmaf(c2.y, m2, acc1.y);
            acc1.z = fmaf(c2.z, m2, acc1.z); acc1.w = fmaf(c2.w, m2, acc1.w);
            acc0.x = fmaf(a3.x, m3, acc0.x); acc0.y = fmaf(a3.y, m3, acc0.y);
            acc0.z = fmaf(a3.z, m3, acc0.z); acc0.w = fmaf(a3.w, m3, acc0.w);
            acc1.x = fmaf(c3.x, m3, acc1.x); acc1.y = fmaf(c3.y, m3, acc1.y);
            acc1.z = fmaf(c3.z, m3, acc1.z); acc1.w = fmaf(c3.w, m3, acc1.w);
        }

        const float nrm = rsqrtf((float)(degn > 1 ? degn : 1));
        hs[g][q]      = make_float4(acc0.x * nrm, acc0.y * nrm,
                                    acc0.z * nrm, acc0.w * nrm);
        hs[g][q + 16] = make_float4(acc1.x * nrm, acc1.y * nrm,
                                    acc1.z * nrm, acc1.w * nrm);
    }
    __syncthreads();

    // ---- Phase 2: GEMM ----
    const int j = threadIdx.x & 127;   // output column
    const int half = threadIdx.x >> 7; // node half

    float acc[8];
#pragma unroll
    for (int i = 0; i < 8; ++i) acc[i] = 0.0f;

#pragma unroll
    for (int m = 0; m < D4; ++m) {
        const float4 wm = reinterpret_cast<const float4*>(W)[(size_t)j * D4 + m];
#pragma unroll
        for (int i = 0; i < 8; ++i) {
            const float4 h = hs[half * 8 + i][m];
            acc[i] = fmaf(h.x, wm.x,
                     fmaf(h.y, wm.y,
                     fmaf(h.z, wm.z,
                     fmaf(h.w, wm.w, acc[i]))));
        }
    }

    const float bj = b[j];
#pragma unroll
    for (int i = 0; i < 8; ++i) {
        out[(size_t)(n0 + half * 8 + i) * D + j] = acc[i] + bj;
    }
}

// ---------------------------------------------------------------------------
// Launch
// ---------------------------------------------------------------------------
extern "C" void kernel_launch(void* const* d_in, const int* in_sizes, int n_in,
                              void* d_out, int out_size, void* d_ws, size_t ws_size,
                              hipStream_t stream) {
    const float* feat = (const float*)d_in[0];
    const int*   src  = (const int*)d_in[1];
    const int*   dst  = (const int*)d_in[2];
    const float* W    = (const float*)d_in[3];
    const float* b    = (const float*)d_in[4];
    float* out = (float*)d_out;

    // Workspace layout (ints): counts | cursor | offsets | bsum(128) | csr
    int* counts  = (int*)d_ws;
    int* cursor  = counts + N_NODES;
    int* offsets = cursor + N_NODES;
    int* bsum    = offsets + N_NODES;
    int* csr     = bsum + 128;

    hipMemsetAsync(counts, 0, 2 * (size_t)N_NODES * sizeof(int), stream);

    const int e4blocks = (N_EDGES / 4 + 255) / 256;  // 586

    hist_kernel<<<e4blocks, 256, 0, stream>>>(dst, counts);
    scanA_kernel<<<NB, SCAN_BLK, 0, stream>>>(counts, bsum);
    scanC_kernel<<<NB, SCAN_BLK, 0, stream>>>(counts, bsum, offsets);
    fill_kernel<<<e4blocks, 256, 0, stream>>>(src, dst, offsets, cursor, csr);

    fused_kernel<<<N_NODES / TN, 256, 0, stream>>>(
        feat, csr, offsets, counts, W, b, out);
}

// Round 5
// 293.669 us; speedup vs baseline: 1.0028x; 1.0028x over previous
//
#include <hip/hip_runtime.h>
#include <hip/hip_fp16.h>

#define N_NODES 100000
#define N_EDGES 600000
#define D 128
#define D4 32

#define NB 98  // ceil(100000 / 1024) scan tiles

// Native vector types for nontemporal builtins (HIP_vector_type is rejected).
typedef float f32x4 __attribute__((ext_vector_type(4)));

// 8 halfs = 16B, one lane's slice of a 128-half row (16 lanes per row).
struct alignas(16) H8 { __half2 h[4]; };

// ---------------------------------------------------------------------------
// Z = F @ W^T, stored fp16. Same tile structure as the old fused phase-2.
// F is streamed with nontemporal loads (never reused); Z stays cached.
// ---------------------------------------------------------------------------
#define TN 16
__global__ __launch_bounds__(256) void zgemm_kernel(
    const float* __restrict__ F,
    const float* __restrict__ W,
    __half* __restrict__ Zh) {
    __shared__ f32x4 fs[TN][D4];
    const f32x4* F4 = reinterpret_cast<const f32x4*>(F);
    const int n0 = blockIdx.x * TN;

    {
        const int i = threadIdx.x >> 4;
        const int m16 = threadIdx.x & 15;
        const int n = n0 + i;
#pragma unroll
        for (int r = 0; r < 2; ++r) {
            const int c = m16 + r * 16;
            fs[i][c] = __builtin_nontemporal_load(&F4[(size_t)n * D4 + c]);
        }
    }
    __syncthreads();

    const int j = threadIdx.x & 127;
    const int half_ = threadIdx.x >> 7;

    float acc[8];
#pragma unroll
    for (int i = 0; i < 8; ++i) acc[i] = 0.0f;

#pragma unroll
    for (int m = 0; m < D4; ++m) {
        const f32x4 wm = reinterpret_cast<const f32x4*>(W)[(size_t)j * D4 + m];
#pragma unroll
        for (int i = 0; i < 8; ++i) {
            const f32x4 h = fs[half_ * 8 + i][m];
            acc[i] = fmaf(h.x, wm.x,
                     fmaf(h.y, wm.y,
                     fmaf(h.z, wm.z,
                     fmaf(h.w, wm.w, acc[i]))));
        }
    }

#pragma unroll
    for (int i = 0; i < 8; ++i) {
        Zh[(size_t)(n0 + half_ * 8 + i) * D + j] = __float2half(acc[i]);
    }
}

// ---------------------------------------------------------------------------
// CSR build: hist -> scanA (block sums) -> scanC (offsets) -> fill.
// ---------------------------------------------------------------------------
__global__ __launch_bounds__(256) void hist_kernel(
    const int* __restrict__ dst, int* __restrict__ counts) {
    int i = blockIdx.x * blockDim.x + threadIdx.x;
    if (i < N_EDGES / 4) {
        int4 d = reinterpret_cast<const int4*>(dst)[i];
        atomicAdd(&counts[d.x], 1);
        atomicAdd(&counts[d.y], 1);
        atomicAdd(&counts[d.z], 1);
        atomicAdd(&counts[d.w], 1);
    }
}

// Block sums over 1024-element tiles; 256 threads, int4 + shfl reduce.
__global__ __launch_bounds__(256) void scanA_kernel(
    const int* __restrict__ counts, int* __restrict__ bsum) {
    __shared__ int ws[4];
    const int t = threadIdx.x;
    const int idx4 = blockIdx.x * 256 + t;
    int s = 0;
    if (idx4 < N_NODES / 4) {
        int4 c = reinterpret_cast<const int4*>(counts)[idx4];
        s = c.x + c.y + c.z + c.w;
    }
#pragma unroll
    for (int off = 32; off > 0; off >>= 1) s += __shfl_down(s, off);
    if ((t & 63) == 0) ws[t >> 6] = s;
    __syncthreads();
    if (t == 0) bsum[blockIdx.x] = ws[0] + ws[1] + ws[2] + ws[3];
}

// Exclusive scan -> offsets. Thread-local scan of int4 + wave shfl scan +
// cross-wave LDS + in-kernel block prefix (wave 0 reduces bsum[0..blk)).
__global__ __launch_bounds__(256) void scanC_kernel(
    const int* __restrict__ counts, const int* __restrict__ bsum,
    int* __restrict__ offsets) {
    __shared__ int wsum[4];
    __shared__ int bpre;
    const int t = threadIdx.x;
    const int wid = t >> 6;
    const int lane = t & 63;
    const int idx4 = blockIdx.x * 256 + t;

    int4 c = make_int4(0, 0, 0, 0);
    if (idx4 < N_NODES / 4) c = reinterpret_cast<const int4*>(counts)[idx4];
    const int tsum = c.x + c.y + c.z + c.w;

    // wave inclusive scan of tsum
    int inc = tsum;
#pragma unroll
    for (int off = 1; off < 64; off <<= 1) {
        int u = __shfl_up(inc, off);
        if (lane >= off) inc += u;
    }
    if (lane == 63) wsum[wid] = inc;

    // wave 0 concurrently reduces the block prefix from bsum
    if (wid == 0) {
        const int blk = blockIdx.x;
        int v = (lane < blk) ? bsum[lane] : 0;
        if (lane + 64 < blk) v += bsum[lane + 64];
#pragma unroll
        for (int off = 32; off > 0; off >>= 1) v += __shfl_down(v, off);
        if (lane == 0) bpre = v;
    }
    __syncthreads();

    int woff = 0;
#pragma unroll
    for (int w = 0; w < 4; ++w) woff += (w < wid) ? wsum[w] : 0;

    if (idx4 < N_NODES / 4) {
        const int base = bpre + woff + (inc - tsum);  // exclusive
        int4 o;
        o.x = base;
        o.y = base + c.x;
        o.z = o.y + c.y;
        o.w = o.z + c.z;
        reinterpret_cast<int4*>(offsets)[idx4] = o;
    }
}

__global__ __launch_bounds__(256) void fill_kernel(
    const int* __restrict__ src, const int* __restrict__ dst,
    const int* __restrict__ offsets, int* __restrict__ cursor,
    int* __restrict__ csr) {
    int i = blockIdx.x * blockDim.x + threadIdx.x;
    if (i < N_EDGES / 4) {
        int4 s = reinterpret_cast<const int4*>(src)[i];
        int4 d = reinterpret_cast<const int4*>(dst)[i];
        int p;
        p = atomicAdd(&cursor[d.x], 1); csr[offsets[d.x] + p] = s.x;
        p = atomicAdd(&cursor[d.y], 1); csr[offsets[d.y] + p] = s.y;
        p = atomicAdd(&cursor[d.z], 1); csr[offsets[d.z] + p] = s.z;
        p = atomicAdd(&cursor[d.w], 1); csr[offsets[d.w] + p] = s.w;
    }
}

// ---------------------------------------------------------------------------
// Gather over fp16 Z rows (256B each): out[n] = norm*(Z[n] + sum Z[csr]) + b.
// 16 groups of 16 lanes per block; group g = node n0+g; lane q owns 8 halfs.
// f32 accumulate; nontemporal f32 stores (out is never re-read; keep Z in L3).
// ---------------------------------------------------------------------------
__global__ __launch_bounds__(256) void gather_kernel(
    const __half* __restrict__ Zh,
    const int* __restrict__ csr,
    const int* __restrict__ offsets,
    const int* __restrict__ counts,
    const float* __restrict__ b,
    float* __restrict__ out) {
    const H8* Z8 = reinterpret_cast<const H8*>(Zh);  // row = 16 H8 chunks

    const int g = threadIdx.x >> 4;
    const int q = threadIdx.x & 15;
    const int n = blockIdx.x * 16 + g;
    const int row = offsets[n];
    const int degn = counts[n];

    H8 r = Z8[(size_t)n * 16 + q];
    float2 acc0 = __half22float2(r.h[0]);
    float2 acc1 = __half22float2(r.h[1]);
    float2 acc2 = __half22float2(r.h[2]);
    float2 acc3 = __half22float2(r.h[3]);

    const int nit = (degn + 3) >> 2;
    const int dm1 = degn - 1;
    for (int it = 0; it < nit; ++it) {
        const int base = it * 4;
        const int s0 = csr[row + min(base + 0, dm1)];
        const int s1 = csr[row + min(base + 1, dm1)];
        const int s2 = csr[row + min(base + 2, dm1)];
        const int s3 = csr[row + min(base + 3, dm1)];
        const H8 v0 = Z8[(size_t)s0 * 16 + q];
        const H8 v1 = Z8[(size_t)s1 * 16 + q];
        const H8 v2 = Z8[(size_t)s2 * 16 + q];
        const H8 v3 = Z8[(size_t)s3 * 16 + q];
        const float m1 = (base + 1 < degn) ? 1.0f : 0.0f;
        const float m2 = (base + 2 < degn) ? 1.0f : 0.0f;
        const float m3 = (base + 3 < degn) ? 1.0f : 0.0f;

        float2 f;
        f = __half22float2(v0.h[0]); acc0.x += f.x; acc0.y += f.y;
        f = __half22float2(v0.h[1]); acc1.x += f.x; acc1.y += f.y;
        f = __half22float2(v0.h[2]); acc2.x += f.x; acc2.y += f.y;
        f = __half22float2(v0.h[3]); acc3.x += f.x; acc3.y += f.y;
        f = __half22float2(v1.h[0]); acc0.x = fmaf(f.x, m1, acc0.x); acc0.y = fmaf(f.y, m1, acc0.y);
        f = __half22float2(v1.h[1]); acc1.x = fmaf(f.x, m1, acc1.x); acc1.y = fmaf(f.y, m1, acc1.y);
        f = __half22float2(v1.h[2]); acc2.x = fmaf(f.x, m1, acc2.x); acc2.y = fmaf(f.y, m1, acc2.y);
        f = __half22float2(v1.h[3]); acc3.x = fmaf(f.x, m1, acc3.x); acc3.y = fmaf(f.y, m1, acc3.y);
        f = __half22float2(v2.h[0]); acc0.x = fmaf(f.x, m2, acc0.x); acc0.y = fmaf(f.y, m2, acc0.y);
        f = __half22float2(v2.h[1]); acc1.x = fmaf(f.x, m2, acc1.x); acc1.y = fmaf(f.y, m2, acc1.y);
        f = __half22float2(v2.h[2]); acc2.x = fmaf(f.x, m2, acc2.x); acc2.y = fmaf(f.y, m2, acc2.y);
        f = __half22float2(v2.h[3]); acc3.x = fmaf(f.x, m2, acc3.x); acc3.y = fmaf(f.y, m2, acc3.y);
        f = __half22float2(v3.h[0]); acc0.x = fmaf(f.x, m3, acc0.x); acc0.y = fmaf(f.y, m3, acc0.y);
        f = __half22float2(v3.h[1]); acc1.x = fmaf(f.x, m3, acc1.x); acc1.y = fmaf(f.y, m3, acc1.y);
        f = __half22float2(v3.h[2]); acc2.x = fmaf(f.x, m3, acc2.x); acc2.y = fmaf(f.y, m3, acc2.y);
        f = __half22float2(v3.h[3]); acc3.x = fmaf(f.x, m3, acc3.x); acc3.y = fmaf(f.y, m3, acc3.y);
    }

    const float nrm = rsqrtf((float)(degn > 1 ? degn : 1));
    const f32x4 b0 = reinterpret_cast<const f32x4*>(b)[q * 2 + 0];
    const f32x4 b1 = reinterpret_cast<const f32x4*>(b)[q * 2 + 1];

    f32x4 o0, o1;
    o0.x = fmaf(acc0.x, nrm, b0.x);
    o0.y = fmaf(acc0.y, nrm, b0.y);
    o0.z = fmaf(acc1.x, nrm, b0.z);
    o0.w = fmaf(acc1.y, nrm, b0.w);
    o1.x = fmaf(acc2.x, nrm, b1.x);
    o1.y = fmaf(acc2.y, nrm, b1.y);
    o1.z = fmaf(acc3.x, nrm, b1.z);
    o1.w = fmaf(acc3.y, nrm, b1.w);

    f32x4* op = reinterpret_cast<f32x4*>(out + (size_t)n * D + q * 8);
    __builtin_nontemporal_store(o0, op);
    __builtin_nontemporal_store(o1, op + 1);
}

// ---------------------------------------------------------------------------
// Launch
// ---------------------------------------------------------------------------
extern "C" void kernel_launch(void* const* d_in, const int* in_sizes, int n_in,
                              void* d_out, int out_size, void* d_ws, size_t ws_size,
                              hipStream_t stream) {
    const float* feat = (const float*)d_in[0];
    const int*   src  = (const int*)d_in[1];
    const int*   dst  = (const int*)d_in[2];
    const float* W    = (const float*)d_in[3];
    const float* b    = (const float*)d_in[4];
    float* out = (float*)d_out;

    // ws layout (ints): counts | cursor | offsets | bsum(128) | csr | Zh(fp16)
    int* counts  = (int*)d_ws;
    int* cursor  = counts + N_NODES;
    int* offsets = cursor + N_NODES;
    int* bsum    = offsets + N_NODES;
    int* csr     = bsum + 128;
    __half* Zh   = (__half*)(csr + N_EDGES);  // 25.6 MB, 16B-aligned

    (void)hipMemsetAsync(counts, 0, 2 * (size_t)N_NODES * sizeof(int), stream);

    const int e4blocks = (N_EDGES / 4 + 255) / 256;  // 586

    hist_kernel<<<e4blocks, 256, 0, stream>>>(dst, counts);
    scanA_kernel<<<NB, 256, 0, stream>>>(counts, bsum);
    scanC_kernel<<<NB, 256, 0, stream>>>(counts, bsum, offsets);
    fill_kernel<<<e4blocks, 256, 0, stream>>>(src, dst, offsets, cursor, csr);
    zgemm_kernel<<<N_NODES / TN, 256, 0, stream>>>(feat, W, Zh);
    gather_kernel<<<N_NODES / 16, 256, 0, stream>>>(
        Zh, csr, offsets, counts, b, out);
}

// Round 7
// 218.911 us; speedup vs baseline: 1.3453x; 1.3415x over previous
//
#include <hip/hip_runtime.h>
#include <hip/hip_fp16.h>

#define N_NODES 100000
#define N_EDGES 600000
#define D 128
#define D4 32

#define NB 98  // ceil(100000 / 1024) scan tiles

// Native vector types (HIP_vector_type rejected by nontemporal/mfma builtins).
typedef float f32x4 __attribute__((ext_vector_type(4)));
typedef _Float16 f16x8 __attribute__((ext_vector_type(8)));

// 8 halfs = 16B, one lane's slice of a 128-half row (16 lanes per row).
struct alignas(16) H8 { __half2 h[4]; };

// ---------------------------------------------------------------------------
// Z = F @ W^T via MFMA, stored fp16.
// Per wave: D-tile = (16 j-rows x 16 node-cols) x 8 j-tiles, K=128 in 4 steps.
//   mfma_f32_16x16x32_f16(A=W-frag, B=F-frag, acc): operand lane mapping
//   row/col = lane&15, k = (lane>>4)*8 + e  (e = elem in 8-wide fragment);
//   D: col = lane&15 (node), row = (lane>>4)*4 + r (j within tile)  [m89].
// => lane stores 4 consecutive f16 per j-tile: Zh[n][jt*16 + (lane>>4)*4 .. +3].
// All 32 W fragments (128 VGPRs) loaded once per wave, reused across tiles.
// ---------------------------------------------------------------------------
#define ZGRID 512  // 2048 waves, ~3 node-tiles each (6250 tiles total)

__global__ __launch_bounds__(256) void zgemm_kernel(
    const float* __restrict__ F,
    const float* __restrict__ W,
    __half* __restrict__ Zh) {
    const int lane = threadIdx.x & 63;
    const int wid = threadIdx.x >> 6;
    const int r16 = lane & 15;         // fragment row (W row j / node col n)
    const int kb = (lane >> 4) * 8;    // k base within a 32-k step
    const int jb = (lane >> 4) * 4;    // D row base within a 16-j tile

    // W fragments: Wf[jt][kt] = W[jt*16 + r16][kt*32 + kb .. +7] as f16.
    f16x8 Wf[8][4];
#pragma unroll
    for (int jt = 0; jt < 8; ++jt) {
#pragma unroll
        for (int kt = 0; kt < 4; ++kt) {
            const float* wp = W + (size_t)(jt * 16 + r16) * D + kt * 32 + kb;
            const f32x4 w0 = *reinterpret_cast<const f32x4*>(wp);
            const f32x4 w1 = *reinterpret_cast<const f32x4*>(wp + 4);
            f16x8 f;
            f[0] = (_Float16)w0.x; f[1] = (_Float16)w0.y;
            f[2] = (_Float16)w0.z; f[3] = (_Float16)w0.w;
            f[4] = (_Float16)w1.x; f[5] = (_Float16)w1.y;
            f[6] = (_Float16)w1.z; f[7] = (_Float16)w1.w;
            Wf[jt][kt] = f;
        }
    }

    const int NT = N_NODES / 16;  // 6250
    const int nwaves = ZGRID * 4;
    for (int t = blockIdx.x * 4 + wid; t < NT; t += nwaves) {
        const int n = t * 16 + r16;

        // F fragments for this node tile: Af[kt] = F[n][kt*32 + kb .. +7].
        f16x8 Af[4];
#pragma unroll
        for (int kt = 0; kt < 4; ++kt) {
            const float* fp = F + (size_t)n * D + kt * 32 + kb;
            const f32x4 a0 = *reinterpret_cast<const f32x4*>(fp);
            const f32x4 a1 = *reinterpret_cast<const f32x4*>(fp + 4);
            f16x8 f;
            f[0] = (_Float16)a0.x; f[1] = (_Float16)a0.y;
            f[2] = (_Float16)a0.z; f[3] = (_Float16)a0.w;
            f[4] = (_Float16)a1.x; f[5] = (_Float16)a1.y;
            f[6] = (_Float16)a1.z; f[7] = (_Float16)a1.w;
            Af[kt] = f;
        }

        f32x4 acc[8];
#pragma unroll
        for (int jt = 0; jt < 8; ++jt) acc[jt] = (f32x4){0.f, 0.f, 0.f, 0.f};

#pragma unroll
        for (int kt = 0; kt < 4; ++kt) {
#pragma unroll
            for (int jt = 0; jt < 8; ++jt) {
                acc[jt] = __builtin_amdgcn_mfma_f32_16x16x32_f16(
                    Wf[jt][kt], Af[kt], acc[jt], 0, 0, 0);
            }
        }

        // Store: 4 consecutive f16 per j-tile (8B, aligned).
#pragma unroll
        for (int jt = 0; jt < 8; ++jt) {
            __half2 h01, h23;
            h01.x = __float2half(acc[jt].x);
            h01.y = __float2half(acc[jt].y);
            h23.x = __float2half(acc[jt].z);
            h23.y = __float2half(acc[jt].w);
            __half2* zp = reinterpret_cast<__half2*>(
                Zh + (size_t)n * D + jt * 16 + jb);
            zp[0] = h01;
            zp[1] = h23;
        }
    }
}

// ---------------------------------------------------------------------------
// CSR build: hist -> scanA (block sums) -> scanC (offsets) -> fill.
// ---------------------------------------------------------------------------
__global__ __launch_bounds__(256) void hist_kernel(
    const int* __restrict__ dst, int* __restrict__ counts) {
    int i = blockIdx.x * blockDim.x + threadIdx.x;
    if (i < N_EDGES / 4) {
        int4 d = reinterpret_cast<const int4*>(dst)[i];
        atomicAdd(&counts[d.x], 1);
        atomicAdd(&counts[d.y], 1);
        atomicAdd(&counts[d.z], 1);
        atomicAdd(&counts[d.w], 1);
    }
}

// Block sums over 1024-element tiles; 256 threads, int4 + shfl reduce.
__global__ __launch_bounds__(256) void scanA_kernel(
    const int* __restrict__ counts, int* __restrict__ bsum) {
    __shared__ int ws[4];
    const int t = threadIdx.x;
    const int idx4 = blockIdx.x * 256 + t;
    int s = 0;
    if (idx4 < N_NODES / 4) {
        int4 c = reinterpret_cast<const int4*>(counts)[idx4];
        s = c.x + c.y + c.z + c.w;
    }
#pragma unroll
    for (int off = 32; off > 0; off >>= 1) s += __shfl_down(s, off);
    if ((t & 63) == 0) ws[t >> 6] = s;
    __syncthreads();
    if (t == 0) bsum[blockIdx.x] = ws[0] + ws[1] + ws[2] + ws[3];
}

// Exclusive scan -> offsets. Thread-local scan of int4 + wave shfl scan +
// cross-wave LDS + in-kernel block prefix (wave 0 reduces bsum[0..blk)).
__global__ __launch_bounds__(256) void scanC_kernel(
    const int* __restrict__ counts, const int* __restrict__ bsum,
    int* __restrict__ offsets) {
    __shared__ int wsum[4];
    __shared__ int bpre;
    const int t = threadIdx.x;
    const int wid = t >> 6;
    const int lane = t & 63;
    const int idx4 = blockIdx.x * 256 + t;

    int4 c = make_int4(0, 0, 0, 0);
    if (idx4 < N_NODES / 4) c = reinterpret_cast<const int4*>(counts)[idx4];
    const int tsum = c.x + c.y + c.z + c.w;

    // wave inclusive scan of tsum
    int inc = tsum;
#pragma unroll
    for (int off = 1; off < 64; off <<= 1) {
        int u = __shfl_up(inc, off);
        if (lane >= off) inc += u;
    }
    if (lane == 63) wsum[wid] = inc;

    // wave 0 concurrently reduces the block prefix from bsum
    if (wid == 0) {
        const int blk = blockIdx.x;
        int v = (lane < blk) ? bsum[lane] : 0;
        if (lane + 64 < blk) v += bsum[lane + 64];
#pragma unroll
        for (int off = 32; off > 0; off >>= 1) v += __shfl_down(v, off);
        if (lane == 0) bpre = v;
    }
    __syncthreads();

    int woff = 0;
#pragma unroll
    for (int w = 0; w < 4; ++w) woff += (w < wid) ? wsum[w] : 0;

    if (idx4 < N_NODES / 4) {
        const int base = bpre + woff + (inc - tsum);  // exclusive
        int4 o;
        o.x = base;
        o.y = base + c.x;
        o.z = o.y + c.y;
        o.w = o.z + c.z;
        reinterpret_cast<int4*>(offsets)[idx4] = o;
    }
}

__global__ __launch_bounds__(256) void fill_kernel(
    const int* __restrict__ src, const int* __restrict__ dst,
    const int* __restrict__ offsets, int* __restrict__ cursor,
    int* __restrict__ csr) {
    int i = blockIdx.x * blockDim.x + threadIdx.x;
    if (i < N_EDGES / 4) {
        int4 s = reinterpret_cast<const int4*>(src)[i];
        int4 d = reinterpret_cast<const int4*>(dst)[i];
        int p;
        p = atomicAdd(&cursor[d.x], 1); csr[offsets[d.x] + p] = s.x;
        p = atomicAdd(&cursor[d.y], 1); csr[offsets[d.y] + p] = s.y;
        p = atomicAdd(&cursor[d.z], 1); csr[offsets[d.z] + p] = s.z;
        p = atomicAdd(&cursor[d.w], 1); csr[offsets[d.w] + p] = s.w;
    }
}

// ---------------------------------------------------------------------------
// Gather over fp16 Z rows (256B each): out[n] = norm*(Z[n] + sum Z[csr]) + b.
// 16 groups of 16 lanes per block; group g = node n0+g; lane q owns 8 halfs.
// f32 accumulate; nontemporal f32 stores (out is never re-read; keep Z in L3).
// ---------------------------------------------------------------------------
__global__ __launch_bounds__(256) void gather_kernel(
    const __half* __restrict__ Zh,
    const int* __restrict__ csr,
    const int* __restrict__ offsets,
    const int* __restrict__ counts,
    const float* __restrict__ b,
    float* __restrict__ out) {
    const H8* Z8 = reinterpret_cast<const H8*>(Zh);  // row = 16 H8 chunks

    const int g = threadIdx.x >> 4;
    const int q = threadIdx.x & 15;
    const int n = blockIdx.x * 16 + g;
    const int row = offsets[n];
    const int degn = counts[n];

    H8 r = Z8[(size_t)n * 16 + q];
    float2 acc0 = __half22float2(r.h[0]);
    float2 acc1 = __half22float2(r.h[1]);
    float2 acc2 = __half22float2(r.h[2]);
    float2 acc3 = __half22float2(r.h[3]);

    const int nit = (degn + 3) >> 2;
    const int dm1 = degn - 1;
    for (int it = 0; it < nit; ++it) {
        const int base = it * 4;
        const int s0 = csr[row + min(base + 0, dm1)];
        const int s1 = csr[row + min(base + 1, dm1)];
        const int s2 = csr[row + min(base + 2, dm1)];
        const int s3 = csr[row + min(base + 3, dm1)];
        const H8 v0 = Z8[(size_t)s0 * 16 + q];
        const H8 v1 = Z8[(size_t)s1 * 16 + q];
        const H8 v2 = Z8[(size_t)s2 * 16 + q];
        const H8 v3 = Z8[(size_t)s3 * 16 + q];
        const float m1 = (base + 1 < degn) ? 1.0f : 0.0f;
        const float m2 = (base + 2 < degn) ? 1.0f : 0.0f;
        const float m3 = (base + 3 < degn) ? 1.0f : 0.0f;

        float2 f;
        f = __half22float2(v0.h[0]); acc0.x += f.x; acc0.y += f.y;
        f = __half22float2(v0.h[1]); acc1.x += f.x; acc1.y += f.y;
        f = __half22float2(v0.h[2]); acc2.x += f.x; acc2.y += f.y;
        f = __half22float2(v0.h[3]); acc3.x += f.x; acc3.y += f.y;
        f = __half22float2(v1.h[0]); acc0.x = fmaf(f.x, m1, acc0.x); acc0.y = fmaf(f.y, m1, acc0.y);
        f = __half22float2(v1.h[1]); acc1.x = fmaf(f.x, m1, acc1.x); acc1.y = fmaf(f.y, m1, acc1.y);
        f = __half22float2(v1.h[2]); acc2.x = fmaf(f.x, m1, acc2.x); acc2.y = fmaf(f.y, m1, acc2.y);
        f = __half22float2(v1.h[3]); acc3.x = fmaf(f.x, m1, acc3.x); acc3.y = fmaf(f.y, m1, acc3.y);
        f = __half22float2(v2.h[0]); acc0.x = fmaf(f.x, m2, acc0.x); acc0.y = fmaf(f.y, m2, acc0.y);
        f = __half22float2(v2.h[1]); acc1.x = fmaf(f.x, m2, acc1.x); acc1.y = fmaf(f.y, m2, acc1.y);
        f = __half22float2(v2.h[2]); acc2.x = fmaf(f.x, m2, acc2.x); acc2.y = fmaf(f.y, m2, acc2.y);
        f = __half22float2(v2.h[3]); acc3.x = fmaf(f.x, m2, acc3.x); acc3.y = fmaf(f.y, m2, acc3.y);
        f = __half22float2(v3.h[0]); acc0.x = fmaf(f.x, m3, acc0.x); acc0.y = fmaf(f.y, m3, acc0.y);
        f = __half22float2(v3.h[1]); acc1.x = fmaf(f.x, m3, acc1.x); acc1.y = fmaf(f.y, m3, acc1.y);
        f = __half22float2(v3.h[2]); acc2.x = fmaf(f.x, m3, acc2.x); acc2.y = fmaf(f.y, m3, acc2.y);
        f = __half22float2(v3.h[3]); acc3.x = fmaf(f.x, m3, acc3.x); acc3.y = fmaf(f.y, m3, acc3.y);
    }

    const float nrm = rsqrtf((float)(degn > 1 ? degn : 1));
    const f32x4 b0 = reinterpret_cast<const f32x4*>(b)[q * 2 + 0];
    const f32x4 b1 = reinterpret_cast<const f32x4*>(b)[q * 2 + 1];

    f32x4 o0, o1;
    o0.x = fmaf(acc0.x, nrm, b0.x);
    o0.y = fmaf(acc0.y, nrm, b0.y);
    o0.z = fmaf(acc1.x, nrm, b0.z);
    o0.w = fmaf(acc1.y, nrm, b0.w);
    o1.x = fmaf(acc2.x, nrm, b1.x);
    o1.y = fmaf(acc2.y, nrm, b1.y);
    o1.z = fmaf(acc3.x, nrm, b1.z);
    o1.w = fmaf(acc3.y, nrm, b1.w);

    f32x4* op = reinterpret_cast<f32x4*>(out + (size_t)n * D + q * 8);
    __builtin_nontemporal_store(o0, op);
    __builtin_nontemporal_store(o1, op + 1);
}

// ---------------------------------------------------------------------------
// Launch
// ---------------------------------------------------------------------------
extern "C" void kernel_launch(void* const* d_in, const int* in_sizes, int n_in,
                              void* d_out, int out_size, void* d_ws, size_t ws_size,
                              hipStream_t stream) {
    const float* feat = (const float*)d_in[0];
    const int*   src  = (const int*)d_in[1];
    const int*   dst  = (const int*)d_in[2];
    const float* W    = (const float*)d_in[3];
    const float* b    = (const float*)d_in[4];
    float* out = (float*)d_out;

    // ws layout (ints): counts | cursor | offsets | bsum(128) | csr | Zh(fp16)
    int* counts  = (int*)d_ws;
    int* cursor  = counts + N_NODES;
    int* offsets = cursor + N_NODES;
    int* bsum    = offsets + N_NODES;
    int* csr     = bsum + 128;
    __half* Zh   = (__half*)(csr + N_EDGES);  // 25.6 MB, 16B-aligned

    (void)hipMemsetAsync(counts, 0, 2 * (size_t)N_NODES * sizeof(int), stream);

    const int e4blocks = (N_EDGES / 4 + 255) / 256;  // 586

    hist_kernel<<<e4blocks, 256, 0, stream>>>(dst, counts);
    scanA_kernel<<<NB, 256, 0, stream>>>(counts, bsum);
    scanC_kernel<<<NB, 256, 0, stream>>>(counts, bsum, offsets);
    fill_kernel<<<e4blocks, 256, 0, stream>>>(src, dst, offsets, cursor, csr);
    zgemm_kernel<<<ZGRID, 256, 0, stream>>>(feat, W, Zh);
    gather_kernel<<<N_NODES / 16, 256, 0, stream>>>(
        Zh, csr, offsets, counts, b, out);
}